// Round 1
// baseline (835.114 us; speedup 1.0000x reference)
//
#include <hip/hip_runtime.h>
#include <math.h>

#define Bn   128
#define Sn   512
#define HIDn 768
#define OUTn 200
#define MSEG 16
#define TS   16   // H rows staged in LDS per block (49KB < 64KB static limit)

// kernel 0: bias[b][o] = b[o] + u[b]@Wu[:,o] + p[b]@Wp[:,o]
__global__ __launch_bounds__(256) void bias_kernel(
    const float* __restrict__ u, const float* __restrict__ p,
    const float* __restrict__ Wu, const float* __restrict__ Wp,
    const float* __restrict__ bvec, float* __restrict__ bias) {
  int b = blockIdx.x;
  __shared__ float ul[OUTn], pl[OUTn];
  int tid = threadIdx.x;
  if (tid < OUTn) { ul[tid] = u[b * OUTn + tid]; pl[tid] = p[b * OUTn + tid]; }
  __syncthreads();
  if (tid < OUTn) {
    float s = bvec[tid];
    for (int k = 0; k < OUTn; ++k)
      s += ul[k] * Wu[k * OUTn + tid] + pl[k] * Wp[k * OUTn + tid];
    bias[b * OUTn + tid] = s;
  }
}

// kernel 1: scores[b][s] = v . tanh(H[b,s,:]@Wh + bias[b,:])
// Block = 256 threads (4 waves). Each block: 16 H-rows in LDS.
// Wave w owns rows w*4..w*4+3; each lane owns 4 output columns (lane + c*64).
__global__ __launch_bounds__(256) void score_kernel(
    const float* __restrict__ H, const float* __restrict__ Wh,
    const float* __restrict__ bias, const float* __restrict__ v,
    float* __restrict__ scores) {
  __shared__ float hl[TS * HIDn];  // 49152 B
  int blk = blockIdx.x;
  int b  = blk / (Sn / TS);
  int s0 = (blk % (Sn / TS)) * TS;
  int tid = threadIdx.x;

  const float4* Hb = (const float4*)(H + ((size_t)b * Sn + s0) * HIDn);
  float4* hl4 = (float4*)hl;
  for (int i = tid; i < TS * HIDn / 4; i += 256) hl4[i] = Hb[i];
  __syncthreads();

  int wave = tid >> 6, lane = tid & 63;
  int r0 = wave * (TS / 4);

  float acc[TS / 4][4];
  for (int r = 0; r < TS / 4; ++r)
    for (int c = 0; c < 4; ++c) acc[r][c] = 0.f;

  int col[4]; bool cv[4];
  for (int c = 0; c < 4; ++c) { col[c] = lane + c * 64; cv[c] = col[c] < OUTn; }

  for (int k = 0; k < HIDn; k += 4) {
    float wh[4][4];
    for (int j = 0; j < 4; ++j)
      for (int c = 0; c < 4; ++c)
        wh[j][c] = cv[c] ? Wh[(k + j) * OUTn + col[c]] : 0.f;
    for (int r = 0; r < TS / 4; ++r) {
      float4 h4 = *(const float4*)&hl[(r0 + r) * HIDn + k];
      for (int c = 0; c < 4; ++c)
        acc[r][c] += h4.x * wh[0][c] + h4.y * wh[1][c] +
                     h4.z * wh[2][c] + h4.w * wh[3][c];
    }
  }

  float vv[4], bb[4];
  for (int c = 0; c < 4; ++c) {
    vv[c] = cv[c] ? v[col[c]] : 0.f;
    bb[c] = cv[c] ? bias[b * OUTn + col[c]] : 0.f;
  }
  for (int r = 0; r < TS / 4; ++r) {
    float s = 0.f;
    for (int c = 0; c < 4; ++c) s += tanhf(acc[r][c] + bb[c]) * vv[c];
    for (int off = 32; off > 0; off >>= 1) s += __shfl_down(s, off);
    if (lane == 0) scores[(size_t)b * Sn + s0 + r0 + r] = s;
  }
}

// kernel 2: per (b, segment m): softmax over scores[beg..end) then
// out[b,m,h] = sum_i alpha[i] * H[b,beg+i,h]
__global__ __launch_bounds__(256) void attend_kernel(
    const float* __restrict__ H, const float* __restrict__ scores,
    const int* __restrict__ offs, float* __restrict__ out) {
  int blk = blockIdx.x;
  int b = blk / MSEG, m = blk % MSEG;
  int beg = offs[b * (MSEG + 1) + m];
  int nxt = offs[b * (MSEG + 1) + m + 1];
  int len = 0;
  if (beg != -1) {
    int end = (nxt == -1) ? Sn : nxt - 1;
    len = end - beg;
    if (len < 0) len = 0;
  }
  __shared__ float sd[Sn];
  __shared__ float red[8];
  int tid = threadIdx.x, wave = tid >> 6, lane = tid & 63;

  float lm = -INFINITY;
  for (int i = tid; i < len; i += 256) {
    float x = scores[(size_t)b * Sn + beg + i];
    sd[i] = x;
    lm = fmaxf(lm, x);
  }
  for (int off = 32; off > 0; off >>= 1) lm = fmaxf(lm, __shfl_down(lm, off));
  if (lane == 0) red[wave] = lm;
  __syncthreads();
  float mx = fmaxf(fmaxf(red[0], red[1]), fmaxf(red[2], red[3]));

  float ls = 0.f;
  for (int i = tid; i < len; i += 256) {
    float e = expf(sd[i] - mx);
    sd[i] = e;
    ls += e;
  }
  for (int off = 32; off > 0; off >>= 1) ls += __shfl_down(ls, off);
  __syncthreads();
  if (lane == 0) red[wave] = ls;
  __syncthreads();
  float denom = red[0] + red[1] + red[2] + red[3];
  float inv = (len > 0 && denom > 0.f) ? 1.f / denom : 0.f;
  for (int i = tid; i < len; i += 256) sd[i] *= inv;
  __syncthreads();

  const float* Hb = H + ((size_t)b * Sn + beg) * HIDn;
  for (int h = tid; h < HIDn; h += 256) {
    float s = 0.f;
    for (int i = 0; i < len; ++i) s += sd[i] * Hb[(size_t)i * HIDn + h];
    out[((size_t)b * MSEG + m) * HIDn + h] = s;
  }
}

extern "C" void kernel_launch(void* const* d_in, const int* in_sizes, int n_in,
                              void* d_out, int out_size, void* d_ws, size_t ws_size,
                              hipStream_t stream) {
  const float* H    = (const float*)d_in[0];
  const float* u    = (const float*)d_in[1];
  const float* p    = (const float*)d_in[2];
  const float* Wh   = (const float*)d_in[3];
  const float* Wu   = (const float*)d_in[4];
  const float* Wp   = (const float*)d_in[5];
  const float* v    = (const float*)d_in[6];
  const float* bvec = (const float*)d_in[7];
  const int*   offs = (const int*)d_in[8];
  float* out = (float*)d_out;

  float* scores = (float*)d_ws;                 // B*S floats   (256 KB)
  float* bias   = scores + (size_t)Bn * Sn;     // B*OUT floats (100 KB)

  bias_kernel<<<Bn, 256, 0, stream>>>(u, p, Wu, Wp, bvec, bias);
  score_kernel<<<Bn * (Sn / TS), 256, 0, stream>>>(H, Wh, bias, v, scores);
  attend_kernel<<<Bn * MSEG, 256, 0, stream>>>(H, scores, offs, out);
}

// Round 2
// 395.505 us; speedup vs baseline: 2.1115x; 2.1115x over previous
//
#include <hip/hip_runtime.h>
#include <hip/hip_bf16.h>
#include <math.h>

#define Bn   128
#define Sn   512
#define HIDn 768
#define OUTn 200
#define MSEG 16
#define NPAD 208   // OUT padded to 13 MFMA n-tiles of 16
#define NT   13

typedef __attribute__((ext_vector_type(8))) short short8;
typedef __attribute__((ext_vector_type(4))) float f32x4;

// fp32 -> bf16 round-to-nearest-even (inputs are finite Gaussians; no NaN path)
static __device__ inline unsigned short f2bf(float f) {
  union { float f; unsigned u; } v; v.f = f;
  unsigned r = v.u + 0x7FFFu + ((v.u >> 16) & 1u);
  return (unsigned short)(r >> 16);
}

// one-time: WhT[n][k] = bf16(Wh[k][n]), zero-padded rows 200..207; vP padded copy of v
__global__ __launch_bounds__(256) void setup_kernel(
    const float* __restrict__ Wh, const float* __restrict__ v,
    unsigned short* __restrict__ WhT, float* __restrict__ vP) {
  __shared__ float tile[16][17];
  int n0 = blockIdx.x * 16;
  int tid = threadIdx.x;
  if (blockIdx.x == 0 && tid < NPAD) vP[tid] = (tid < OUTn) ? v[tid] : 0.f;
  int tk = tid >> 4, tn = tid & 15;   // load phase: (k,n)
  for (int k0 = 0; k0 < HIDn; k0 += 16) {
    float val = 0.f;
    int n = n0 + tn;
    if (n < OUTn) val = Wh[(size_t)(k0 + tk) * OUTn + n];
    tile[tk][tn] = val;
    __syncthreads();
    int tn2 = tid >> 4, tk2 = tid & 15; // store phase: (n,k)
    WhT[(size_t)(n0 + tn2) * HIDn + k0 + tk2] = f2bf(tile[tk2][tn2]);
    __syncthreads();
  }
}

// biasP[b][n] = b[n] + u[b]@Wu[:,n] + p[b]@Wp[:,n], zero-padded to NPAD
__global__ __launch_bounds__(256) void bias_kernel(
    const float* __restrict__ u, const float* __restrict__ p,
    const float* __restrict__ Wu, const float* __restrict__ Wp,
    const float* __restrict__ bvec, float* __restrict__ biasP) {
  int b = blockIdx.x;
  __shared__ float ul[OUTn], pl[OUTn];
  int tid = threadIdx.x;
  if (tid < OUTn) { ul[tid] = u[b * OUTn + tid]; pl[tid] = p[b * OUTn + tid]; }
  __syncthreads();
  if (tid < NPAD) {
    float s = 0.f;
    if (tid < OUTn) {
      s = bvec[tid];
      for (int k = 0; k < OUTn; ++k)
        s += ul[k] * Wu[k * OUTn + tid] + pl[k] * Wp[k * OUTn + tid];
    }
    biasP[(size_t)b * NPAD + tid] = s;
  }
}

// scores[m] = v . tanh(H[m,:]@Wh + bias[b,:]) via bf16 MFMA.
// Block: 128 rows x 208 cols. 4 waves stacked in M (32 rows each, 2 m-tiles).
// A: global->register fp32->bf16 (rows private to wave). B: WhT staged in LDS.
__global__ __launch_bounds__(256) void score_mfma(
    const float* __restrict__ H, const unsigned short* __restrict__ WhT,
    const float* __restrict__ biasP, const float* __restrict__ vP,
    float* __restrict__ scores) {
  __shared__ unsigned short Bl[NPAD * 32];  // 13.3 KB, n-major, 32 k per row
  int tid = threadIdx.x, wave = tid >> 6, lane = tid & 63;
  int quad = lane >> 4, l16 = lane & 15;
  int m0 = blockIdx.x * 128;
  int b = m0 >> 9;  // 512 rows per batch, 4 blocks per b

  f32x4 acc[2][NT];
  for (int mt = 0; mt < 2; ++mt)
    for (int nt = 0; nt < NT; ++nt) acc[mt][nt] = (f32x4){0.f, 0.f, 0.f, 0.f};

  const float* Abase = H + (size_t)(m0 + wave * 32 + l16) * HIDn + quad * 8;

  for (int k0 = 0; k0 < HIDn; k0 += 32) {
    __syncthreads();  // previous iter's Bl reads done
    for (int i = tid; i < NPAD * 4; i += 256) {  // 832 16B chunks
      int n = i >> 2, c = i & 3;
      int4 d = *(const int4*)(WhT + (size_t)n * HIDn + k0 + c * 8);
      *(int4*)(&Bl[n * 32 + c * 8]) = d;
    }
    __syncthreads();

    short8 a[2];
#pragma unroll
    for (int mt = 0; mt < 2; ++mt) {
      const float* ap = Abase + (size_t)mt * 16 * HIDn + k0;
      float4 f0 = *(const float4*)ap;
      float4 f1 = *(const float4*)(ap + 4);
      short8 t;
      t[0] = f2bf(f0.x); t[1] = f2bf(f0.y); t[2] = f2bf(f0.z); t[3] = f2bf(f0.w);
      t[4] = f2bf(f1.x); t[5] = f2bf(f1.y); t[6] = f2bf(f1.z); t[7] = f2bf(f1.w);
      a[mt] = t;
    }
#pragma unroll
    for (int nt = 0; nt < NT; ++nt) {
      short8 bf = *(const short8*)(&Bl[(nt * 16 + l16) * 32 + quad * 8]);
      acc[0][nt] = __builtin_amdgcn_mfma_f32_16x16x32_bf16(a[0], bf, acc[0][nt], 0, 0, 0);
      acc[1][nt] = __builtin_amdgcn_mfma_f32_16x16x32_bf16(a[1], bf, acc[1][nt], 0, 0, 0);
    }
  }

  // epilogue: scores[m] = sum_n tanh(C[m][n] + bias) * v   (pad cols have v=0)
  const float* bp = biasP + (size_t)b * NPAD;
#pragma unroll
  for (int mt = 0; mt < 2; ++mt) {
#pragma unroll
    for (int r = 0; r < 4; ++r) {
      float s = 0.f;
#pragma unroll
      for (int nt = 0; nt < NT; ++nt) {
        int n = nt * 16 + l16;
        s += tanhf(acc[mt][nt][r] + bp[n]) * vP[n];
      }
      s += __shfl_xor(s, 1); s += __shfl_xor(s, 2);
      s += __shfl_xor(s, 4); s += __shfl_xor(s, 8);
      if (l16 == 0) {
        int m = m0 + wave * 32 + mt * 16 + quad * 4 + r;
        scores[m] = s;
      }
    }
  }
}

// per (b, segment): softmax over scores[beg..end) then out = alphas @ H
__global__ __launch_bounds__(256) void attend_kernel(
    const float* __restrict__ H, const float* __restrict__ scores,
    const int* __restrict__ offs, float* __restrict__ out) {
  int blk = blockIdx.x;
  int b = blk / MSEG, m = blk % MSEG;
  int beg = offs[b * (MSEG + 1) + m];
  int nxt = offs[b * (MSEG + 1) + m + 1];
  int len = 0;
  if (beg != -1) {
    int end = (nxt == -1) ? Sn : nxt - 1;
    len = end - beg;
    if (len < 0) len = 0;
  }
  __shared__ float sd[Sn];
  __shared__ float red[8];
  int tid = threadIdx.x, wave = tid >> 6, lane = tid & 63;

  float lm = -INFINITY;
  for (int i = tid; i < len; i += 256) {
    float x = scores[(size_t)b * Sn + beg + i];
    sd[i] = x;
    lm = fmaxf(lm, x);
  }
  for (int off = 32; off > 0; off >>= 1) lm = fmaxf(lm, __shfl_down(lm, off));
  if (lane == 0) red[wave] = lm;
  __syncthreads();
  float mx = fmaxf(fmaxf(red[0], red[1]), fmaxf(red[2], red[3]));

  float ls = 0.f;
  for (int i = tid; i < len; i += 256) {
    float e = expf(sd[i] - mx);
    sd[i] = e;
    ls += e;
  }
  for (int off = 32; off > 0; off >>= 1) ls += __shfl_down(ls, off);
  __syncthreads();
  if (lane == 0) red[wave] = ls;
  __syncthreads();
  float denom = red[0] + red[1] + red[2] + red[3];
  float inv = (len > 0 && denom > 0.f) ? 1.f / denom : 0.f;
  for (int i = tid; i < len; i += 256) sd[i] *= inv;
  __syncthreads();

  const float4* Hb4 = (const float4*)(H + ((size_t)b * Sn + beg) * HIDn);
  float4* out4 = (float4*)(out + ((size_t)b * MSEG + m) * HIDn);
  for (int h4 = tid; h4 < HIDn / 4; h4 += 256) {
    float4 s = {0.f, 0.f, 0.f, 0.f};
#pragma unroll 4
    for (int i = 0; i < len; ++i) {
      float4 hv = Hb4[(size_t)i * (HIDn / 4) + h4];
      float a = sd[i];
      s.x += a * hv.x; s.y += a * hv.y; s.z += a * hv.z; s.w += a * hv.w;
    }
    out4[h4] = s;
  }
}

extern "C" void kernel_launch(void* const* d_in, const int* in_sizes, int n_in,
                              void* d_out, int out_size, void* d_ws, size_t ws_size,
                              hipStream_t stream) {
  const float* H    = (const float*)d_in[0];
  const float* u    = (const float*)d_in[1];
  const float* p    = (const float*)d_in[2];
  const float* Wh   = (const float*)d_in[3];
  const float* Wu   = (const float*)d_in[4];
  const float* Wp   = (const float*)d_in[5];
  const float* v    = (const float*)d_in[6];
  const float* bvec = (const float*)d_in[7];
  const int*   offs = (const int*)d_in[8];
  float* out = (float*)d_out;

  // ws layout (floats): scores[65536] | biasP[128*208] | vP[208] | WhT (bf16)
  float* scores = (float*)d_ws;
  float* biasP  = scores + (size_t)Bn * Sn;
  float* vP     = biasP + (size_t)Bn * NPAD;
  unsigned short* WhT = (unsigned short*)(vP + NPAD);

  setup_kernel<<<NPAD / 16, 256, 0, stream>>>(Wh, v, WhT, vP);
  bias_kernel<<<Bn, 256, 0, stream>>>(u, p, Wu, Wp, bvec, biasP);
  score_mfma<<<(Bn * Sn) / 128, 256, 0, stream>>>(H, WhT, biasP, vP, scores);
  attend_kernel<<<Bn * MSEG, 256, 0, stream>>>(H, scores, offs, out);
}

// Round 3
// 379.846 us; speedup vs baseline: 2.1986x; 1.0412x over previous
//
#include <hip/hip_runtime.h>
#include <hip/hip_bf16.h>
#include <math.h>

#define Bn   128
#define Sn   512
#define HIDn 768
#define OUTn 200
#define MSEG 16
#define NPAD 208   // OUT padded to 13 MFMA n-tiles of 16
#define NT   13

typedef __attribute__((ext_vector_type(8))) short short8;
typedef __attribute__((ext_vector_type(4))) float f32x4;

// fp32 -> bf16 round-to-nearest-even (finite inputs)
static __device__ inline unsigned short f2bf(float f) {
  union { float f; unsigned u; } v; v.f = f;
  unsigned r = v.u + 0x7FFFu + ((v.u >> 16) & 1u);
  return (unsigned short)(r >> 16);
}

// saturating fast tanh: e = exp(-2|x|) in (0,1], never overflows; ~6 VALU ops
static __device__ inline float fast_tanh(float x) {
  float t = fabsf(x);
  float e = __expf(-2.f * t);
  float r = (1.f - e) * __builtin_amdgcn_rcpf(1.f + e);
  return copysignf(r, x);
}

// one-time: WhT[n][k] = bf16(Wh[k][n]), zero-padded rows 200..207; vP padded v
__global__ __launch_bounds__(256) void setup_kernel(
    const float* __restrict__ Wh, const float* __restrict__ v,
    unsigned short* __restrict__ WhT, float* __restrict__ vP) {
  __shared__ float tile[16][17];
  int n0 = blockIdx.x * 16;
  int tid = threadIdx.x;
  if (blockIdx.x == 0 && tid < NPAD) vP[tid] = (tid < OUTn) ? v[tid] : 0.f;
  int tk = tid >> 4, tn = tid & 15;
  for (int k0 = 0; k0 < HIDn; k0 += 16) {
    float val = 0.f;
    int n = n0 + tn;
    if (n < OUTn) val = Wh[(size_t)(k0 + tk) * OUTn + n];
    tile[tk][tn] = val;
    __syncthreads();
    int tn2 = tid >> 4, tk2 = tid & 15;
    WhT[(size_t)(n0 + tn2) * HIDn + k0 + tk2] = f2bf(tile[tk2][tn2]);
    __syncthreads();
  }
}

// biasP[b][n] = b[n] + u[b]@Wu[:,n] + p[b]@Wp[:,n], zero-padded to NPAD
__global__ __launch_bounds__(256) void bias_kernel(
    const float* __restrict__ u, const float* __restrict__ p,
    const float* __restrict__ Wu, const float* __restrict__ Wp,
    const float* __restrict__ bvec, float* __restrict__ biasP) {
  int b = blockIdx.x;
  __shared__ float ul[OUTn], pl[OUTn];
  int tid = threadIdx.x;
  if (tid < OUTn) { ul[tid] = u[b * OUTn + tid]; pl[tid] = p[b * OUTn + tid]; }
  __syncthreads();
  if (tid < NPAD) {
    float s = 0.f;
    if (tid < OUTn) {
      s = bvec[tid];
      for (int k = 0; k < OUTn; ++k)
        s += ul[k] * Wu[k * OUTn + tid] + pl[k] * Wp[k * OUTn + tid];
    }
    biasP[(size_t)b * NPAD + tid] = s;
  }
}

// Fused: scores via bf16 MFMA, per-wave segment softmax, weighted-sum output.
// Block = 128 rows of one batch b; wave w owns rows [w*32, w*32+32) = one segment.
__global__ __launch_bounds__(256) void fused_kernel(
    const float* __restrict__ H, const unsigned short* __restrict__ WhT,
    const float* __restrict__ biasP, const float* __restrict__ vP,
    const int* __restrict__ offs, float* __restrict__ out) {
  __shared__ unsigned short Bl[NPAD * 32];  // 13.3 KB, n-major, 32 k per row
  __shared__ float al[128];                 // per-wave alphas
  int tid = threadIdx.x, wave = tid >> 6, lane = tid & 63;
  int quad = lane >> 4, l16 = lane & 15;
  int m0 = blockIdx.x * 128;
  int b = m0 >> 9;
  int s0 = m0 & 511;

  f32x4 acc[2][NT];
  for (int mt = 0; mt < 2; ++mt)
    for (int nt = 0; nt < NT; ++nt) acc[mt][nt] = (f32x4){0.f, 0.f, 0.f, 0.f};

  const float* Abase = H + (size_t)(m0 + wave * 32 + l16) * HIDn + quad * 8;

  for (int k0 = 0; k0 < HIDn; k0 += 32) {
    // issue A loads first: latency overlaps B staging + barriers
    float4 f[2][2];
#pragma unroll
    for (int mt = 0; mt < 2; ++mt) {
      const float* ap = Abase + (size_t)mt * 16 * HIDn + k0;
      f[mt][0] = *(const float4*)ap;
      f[mt][1] = *(const float4*)(ap + 4);
    }
    __syncthreads();  // previous iter's Bl reads done
    for (int i = tid; i < NPAD * 4; i += 256) {
      int n = i >> 2, c = i & 3;
      int4 d = *(const int4*)(WhT + (size_t)n * HIDn + k0 + c * 8);
      *(int4*)(&Bl[n * 32 + c * 8]) = d;
    }
    __syncthreads();

    short8 a[2];
#pragma unroll
    for (int mt = 0; mt < 2; ++mt) {
      short8 t;
      t[0] = f2bf(f[mt][0].x); t[1] = f2bf(f[mt][0].y);
      t[2] = f2bf(f[mt][0].z); t[3] = f2bf(f[mt][0].w);
      t[4] = f2bf(f[mt][1].x); t[5] = f2bf(f[mt][1].y);
      t[6] = f2bf(f[mt][1].z); t[7] = f2bf(f[mt][1].w);
      a[mt] = t;
    }
#pragma unroll
    for (int nt = 0; nt < NT; ++nt) {
      short8 bf = *(const short8*)(&Bl[(nt * 16 + l16) * 32 + quad * 8]);
      acc[0][nt] = __builtin_amdgcn_mfma_f32_16x16x32_bf16(a[0], bf, acc[0][nt], 0, 0, 0);
      acc[1][nt] = __builtin_amdgcn_mfma_f32_16x16x32_bf16(a[1], bf, acc[1][nt], 0, 0, 0);
    }
  }

  // ---- scores: sc[mt][r] = v . tanh(C + bias), reduced over l16 (all lanes hold it)
  const float* bp = biasP + (size_t)b * NPAD;
  float sc[2][4];
#pragma unroll
  for (int mt = 0; mt < 2; ++mt) {
#pragma unroll
    for (int r = 0; r < 4; ++r) {
      float s = 0.f;
#pragma unroll
      for (int nt = 0; nt < NT; ++nt) {
        int n = nt * 16 + l16;
        s += fast_tanh(acc[mt][nt][r] + bp[n]) * vP[n];
      }
      s += __shfl_xor(s, 1); s += __shfl_xor(s, 2);
      s += __shfl_xor(s, 4); s += __shfl_xor(s, 8);
      sc[mt][r] = s;  // score for row wave*32 + mt*16 + quad*4 + r
    }
  }

  // ---- per-wave segment softmax (wave w owns segment seg)
  int seg = (s0 >> 5) + wave;
  int beg = offs[b * (MSEG + 1) + seg];
  int nxt = offs[b * (MSEG + 1) + seg + 1];
  bool valid = (beg != -1);
  int end = (nxt == -1) ? Sn : nxt - 1;

  float x[2][4];
  float mx = -INFINITY;
#pragma unroll
  for (int mt = 0; mt < 2; ++mt)
#pragma unroll
    for (int r = 0; r < 4; ++r) {
      int row = s0 + wave * 32 + mt * 16 + quad * 4 + r;
      bool in = valid && row >= beg && row < end;
      x[mt][r] = in ? sc[mt][r] : -INFINITY;
      mx = fmaxf(mx, x[mt][r]);
    }
  mx = fmaxf(mx, __shfl_xor(mx, 16));
  mx = fmaxf(mx, __shfl_xor(mx, 32));
  float mm = (mx > -1e30f) ? mx : 0.f;

  float e[2][4], ls = 0.f;
#pragma unroll
  for (int mt = 0; mt < 2; ++mt)
#pragma unroll
    for (int r = 0; r < 4; ++r) {
      e[mt][r] = __expf(x[mt][r] - mm);  // exp(-inf) = 0 handles masking
      ls += e[mt][r];
    }
  ls += __shfl_xor(ls, 16);
  ls += __shfl_xor(ls, 32);
  float inv = (ls > 0.f) ? 1.f / ls : 0.f;

  if (l16 == 0) {
#pragma unroll
    for (int mt = 0; mt < 2; ++mt)
#pragma unroll
      for (int r = 0; r < 4; ++r)
        al[wave * 32 + mt * 16 + quad * 4 + r] = e[mt][r] * inv;
  }
  // al written+read by same wave only -> no __syncthreads needed

  // ---- weighted sum over the wave's 32 rows (L2-hot: just streamed by GEMM)
  const float4* Hrow = (const float4*)(H + (size_t)(b * Sn + s0 + wave * 32) * HIDn);
  float4 o0 = {0,0,0,0}, o1 = {0,0,0,0}, o2 = {0,0,0,0};
  for (int i = 0; i < 32; ++i) {
    float a = al[wave * 32 + i];       // LDS broadcast, wave-uniform
    if (a != 0.f) {                    // uniform branch (skips masked row 31)
      const float4* hp = Hrow + (size_t)i * (HIDn / 4);
      float4 h0 = hp[lane], h1 = hp[lane + 64], h2 = hp[lane + 128];
      o0.x += a * h0.x; o0.y += a * h0.y; o0.z += a * h0.z; o0.w += a * h0.w;
      o1.x += a * h1.x; o1.y += a * h1.y; o1.z += a * h1.z; o1.w += a * h1.w;
      o2.x += a * h2.x; o2.y += a * h2.y; o2.z += a * h2.z; o2.w += a * h2.w;
    }
  }
  float4* op = (float4*)(out + ((size_t)b * MSEG + seg) * HIDn);
  op[lane] = o0; op[lane + 64] = o1; op[lane + 128] = o2;
}

extern "C" void kernel_launch(void* const* d_in, const int* in_sizes, int n_in,
                              void* d_out, int out_size, void* d_ws, size_t ws_size,
                              hipStream_t stream) {
  const float* H    = (const float*)d_in[0];
  const float* u    = (const float*)d_in[1];
  const float* p    = (const float*)d_in[2];
  const float* Wh   = (const float*)d_in[3];
  const float* Wu   = (const float*)d_in[4];
  const float* Wp   = (const float*)d_in[5];
  const float* v    = (const float*)d_in[6];
  const float* bvec = (const float*)d_in[7];
  const int*   offs = (const int*)d_in[8];
  float* out = (float*)d_out;

  // ws layout: biasP[128*208] | vP[208] | WhT (bf16 208*768)
  float* biasP = (float*)d_ws;
  float* vP    = biasP + (size_t)Bn * NPAD;
  unsigned short* WhT = (unsigned short*)(vP + NPAD);

  setup_kernel<<<NPAD / 16, 256, 0, stream>>>(Wh, v, WhT, vP);
  bias_kernel<<<Bn, 256, 0, stream>>>(u, p, Wu, Wp, bvec, biasP);
  fused_kernel<<<(Bn * Sn) / 128, 256, 0, stream>>>(H, WhT, biasP, vP, offs, out);
}